// Round 9
// baseline (106.190 us; speedup 1.0000x reference)
//
#include <hip/hip_runtime.h>
#include <hip/hip_bf16.h>
#include <hip/hip_cooperative_groups.h>

#define EMBED 512
#define NSEQ 2048
#define NROWS 4096

typedef unsigned short u16;
typedef __bf16 bf16x8 __attribute__((ext_vector_type(8)));
typedef float f32x4 __attribute__((ext_vector_type(4)));
typedef unsigned short ushort8 __attribute__((ext_vector_type(8)));

__device__ __forceinline__ u16 f2bf(float f) {
    unsigned u = __float_as_uint(f);
    unsigned r = (u + 0x7FFFu + ((u >> 16) & 1u)) >> 16;
    return (u16)r;
}
__device__ __forceinline__ float bf2f(u16 v) {
    return __uint_as_float((unsigned)v << 16);
}

#define XELEMS    (NROWS * EMBED)     // 2097152
#define WCATELEMS (1536 * EMBED)      // 786432
#define NCONVB    1408                // (XELEMS+WCATELEMS)/8/256

// ===========================================================================
// FUSED single cooperative kernel: 768 blocks x 256 threads, 3 blocks/CU.
// Phase A: convert  | Phase B: QKV gemm | Phase C: wsmall | Phase D: attn+out
// Bodies are byte-equivalent to the verified 4-kernel path below.
// ===========================================================================
__global__ __launch_bounds__(256, 3) void fused_all(
    const float* __restrict__ x,
    const float* __restrict__ Wq, const float* __restrict__ Wk,
    const float* __restrict__ Wv,
    const float* __restrict__ bq, const float* __restrict__ bk,
    const float* __restrict__ bvv,
    const float* __restrict__ Wo, const float* __restrict__ bo,
    u16* __restrict__ xb, u16* __restrict__ Wcat, u16* __restrict__ QKb,
    float* __restrict__ Vhead, float* __restrict__ vpart,
    float* __restrict__ WT, float* __restrict__ out)
{
    __shared__ __align__(16) u16 As[128 * 64];   // 16 KB (aliased by C)
    __shared__ __align__(16) u16 Bs[64 * 64];    // 8 KB  (aliased by D)
    cooperative_groups::grid_group grid = cooperative_groups::this_grid();
    const int t   = threadIdx.x;
    const int bid = blockIdx.x;

    // ---------------- phase A: fp32 -> bf16 conversion (grid-stride) -------
    {
        const long long NOCT = (long long)(XELEMS + WCATELEMS) / 8;  // 360448
        for (long long idx = (long long)bid * 256 + t; idx < NOCT;
             idx += 768LL * 256) {
            const long long e0 = idx * 8;
            const float* src;
            u16* dst;
            if (e0 < XELEMS) {
                src = x + e0; dst = xb + e0;
            } else {
                const long long j = e0 - XELEMS;
                const int row = (int)(j >> 9);
                const int col = (int)(j & 511);
                const int sel = row >> 9;            // 0:Wq 1:Wk 2:Wv
                const int r   = row & 511;
                const float* W = (sel == 0) ? Wq : (sel == 1) ? Wk : Wv;
                src = W + (size_t)r * EMBED + col; dst = Wcat + j;
            }
            float4 a = *(const float4*)(src);
            float4 b = *(const float4*)(src + 4);
            union { u16 u[8]; uint4 v; } p;
            p.u[0]=f2bf(a.x); p.u[1]=f2bf(a.y); p.u[2]=f2bf(a.z); p.u[3]=f2bf(a.w);
            p.u[4]=f2bf(b.x); p.u[5]=f2bf(b.y); p.u[6]=f2bf(b.z); p.u[7]=f2bf(b.w);
            *(uint4*)(dst) = p.v;
        }
    }
    grid.sync();

    // ---------------- phase B: QKV gemm (all 768 blocks) -------------------
    {
        const int m0 = (bid & 31) * 128;
        const int n0 = (bid >> 5) * 64;                    // 0..1472
        const int sel = n0 >> 9;
        const float* bias = ((sel == 0) ? bq : (sel == 1) ? bk : bvv) + (n0 & 511);

        const int wave = t >> 6, lane = t & 63;
        const int wm   = wave >> 1, wn = wave & 1;
        const int qd   = lane >> 4, lr = lane & 15;

        const int sr8 = lane >> 3;
        const int sg  = (lane & 7) ^ sr8;
        const int soff = sg * 8;

        f32x4 acc[4][2] = {};

        const u16* Ag = xb + (size_t)m0 * EMBED;
        const u16* Wg = Wcat + (size_t)n0 * EMBED;

        u16* Adst = As + (size_t)(wave * 8) * 64;
        u16* Bdst = Bs + (size_t)(wave * 8) * 64;
        const u16* Asrc = Ag + (size_t)(wave * 8 + sr8) * EMBED + soff;
        const u16* Bsrc = Wg + (size_t)(wave * 8 + sr8) * EMBED + soff;

        for (int kc = 0; kc < EMBED; kc += 64) {
#pragma unroll
            for (int j = 0; j < 4; ++j)
                __builtin_amdgcn_global_load_lds(
                    (const __attribute__((address_space(1))) void*)(Asrc + kc + (size_t)j * 32 * EMBED),
                    (__attribute__((address_space(3))) void*)(Adst + j * 32 * 64), 16, 0, 0);
#pragma unroll
            for (int j = 0; j < 2; ++j)
                __builtin_amdgcn_global_load_lds(
                    (const __attribute__((address_space(1))) void*)(Bsrc + kc + (size_t)j * 32 * EMBED),
                    (__attribute__((address_space(3))) void*)(Bdst + j * 32 * 64), 16, 0, 0);
            __syncthreads();

#pragma unroll
            for (int kk = 0; kk < 2; ++kk) {
                const int gr = ((kk * 4 + qd) ^ (lr & 7)) * 8;
                bf16x8 af[4], bfr[2];
#pragma unroll
                for (int i = 0; i < 4; ++i)
                    af[i]  = *(const bf16x8*)&As[(wm * 64 + i * 16 + lr) * 64 + gr];
#pragma unroll
                for (int i = 0; i < 2; ++i)
                    bfr[i] = *(const bf16x8*)&Bs[(wn * 32 + i * 16 + lr) * 64 + gr];
#pragma unroll
                for (int mi = 0; mi < 4; ++mi)
#pragma unroll
                    for (int ni = 0; ni < 2; ++ni)
                        acc[mi][ni] = __builtin_amdgcn_mfma_f32_16x16x32_bf16(
                            af[mi], bfr[ni], acc[mi][ni], 0, 0, 0);
            }
            __syncthreads();
        }

        if (sel < 2) {
#pragma unroll
            for (int ni = 0; ni < 2; ++ni) {
                const int cl = wn * 32 + ni * 16 + lr;
                const float bb = bias[cl];
#pragma unroll
                for (int mi = 0; mi < 4; ++mi)
#pragma unroll
                    for (int e = 0; e < 4; ++e) {
                        const int row = m0 + wm * 64 + mi * 16 + qd * 4 + e;
                        QKb[(size_t)row * 1024 + n0 + cl] = f2bf(acc[mi][ni][e] + bb);
                    }
            }
        } else {
            const int batch = m0 >> 11;
            const int mtb   = (m0 >> 7) & 15;
#pragma unroll
            for (int ni = 0; ni < 2; ++ni) {
                const int cl  = wn * 32 + ni * 16 + lr;
                const int col = (n0 - 1024) + cl;
                const float bb = bias[cl];
                float s = 0.f;
#pragma unroll
                for (int mi = 0; mi < 4; ++mi)
#pragma unroll
                    for (int e = 0; e < 4; ++e) {
                        const int row = m0 + wm * 64 + mi * 16 + qd * 4 + e;
                        s += acc[mi][ni][e];
                        if ((row & (NSEQ - 1)) < 3)
                            Vhead[(size_t)batch * 1536 + (row & (NSEQ - 1)) * 512 + col]
                                = acc[mi][ni][e] + bb;
                    }
                s += __shfl_xor(s, 16);
                s += __shfl_xor(s, 32);
                if (qd == 0)
                    vpart[((size_t)batch * 512 + col) * 32 + mtb * 2 + wm] = s;
            }
        }
    }
    grid.sync();

    // ---------------- phase C: wsmall (blocks 0..127) ----------------------
    if (bid < 128) {
        float (*Vsm)[512] = (float(*)[512])As;    // 8 KB alias
        const int b  = bid >> 6;
        const int jb = bid & 63;

        for (int idx = t; idx < 512; idx += 256) {
            const float v0 = Vhead[(size_t)b * 1536 + idx];
            const float v1 = Vhead[(size_t)b * 1536 + 512 + idx];
            const float v2 = Vhead[(size_t)b * 1536 + 1024 + idx];
            float sum = 0.f;
            const float* vp = vpart + ((size_t)b * 512 + idx) * 32;
#pragma unroll
            for (int s = 0; s < 32; ++s) sum += vp[s];
            Vsm[0][idx] = v0; Vsm[1][idx] = v1; Vsm[2][idx] = v2;
            Vsm[3][idx] = sum + (float)NSEQ * bvv[idx] - (v0 + v1 + v2);
        }
        __syncthreads();

        const int j  = jb * 8 + (t >> 5);
        const int s  = t & 31;
        const int h  = s >> 2, tt = s & 3;
        const float* Wor = Wo + (size_t)j * EMBED + h * 64;
        const float* vr  = &Vsm[tt][h * 64];
        float acc = 0.f;
#pragma unroll
        for (int c = 0; c < 64; ++c) {
            const int cc = (c + 2 * s) & 63;
            acc = fmaf(vr[cc], Wor[cc], acc);
        }
        WT[((size_t)b * 512 + j) * 32 + s] = acc;
    }
    grid.sync();

    // ---------------- phase D: attn + out (blocks 0..255) ------------------
    if (bid < 256) {
        float (*E)[32] = (float(*)[32])Bs;        // 2 KB alias
        const int r0   = bid * 16;
        const int b    = r0 >> 11;
        const int wave = t >> 6, lane = t & 63;
        const int d0   = lane * 8;

#pragma unroll
        for (int i = 0; i < 4; ++i) {
            const int rl = wave * 4 + i;
            const int r  = r0 + rl;
            const int sr = r & (NSEQ - 1);
            const u16* Qr = QKb + (size_t)r * 1024 + d0;
            const u16* Kr = QKb + (size_t)r * 1024 + 512 + d0;

            ushort8 qv = *(const ushort8*)Qr;
            ushort8 kv = *(const ushort8*)Kr;
            float q[8], k[8];
#pragma unroll
            for (int z = 0; z < 8; ++z) { q[z] = bf2f(qv[z]); k[z] = bf2f(kv[z]); }

            float s1 = 0.f;
#pragma unroll
            for (int z = 0; z < 8; ++z) s1 = fmaf(q[z], k[z], s1);

            float s0 = 0.f, s2 = 0.f;
            if (sr > 0) {
                ushort8 pv = *(const ushort8*)(Kr - 1024);
#pragma unroll
                for (int z = 0; z < 8; ++z) s0 = fmaf(q[z], bf2f(pv[z]), s0);
            }
            if (sr < NSEQ - 1) {
                ushort8 nv = *(const ushort8*)(Kr + 1024);
#pragma unroll
                for (int z = 0; z < 8; ++z) s2 = fmaf(q[z], bf2f(nv[z]), s2);
            }
#pragma unroll
            for (int off = 1; off <= 4; off <<= 1) {
                s0 += __shfl_xor(s0, off);
                s1 += __shfl_xor(s1, off);
                s2 += __shfl_xor(s2, off);
            }
            const float m  = fmaxf(fmaxf(s0, s1), fmaxf(s2, 0.f));
            const float e0 = __expf(s0 - m);
            const float e1 = __expf(s1 - m);
            const float e2 = __expf(s2 - m);
            const float eb = __expf(-m);
            const float rd = 1.f / (e0 + e1 + e2 + (float)(NSEQ - 3) * eb);
            const int h = lane >> 3, jj = lane & 7;
            const float coef = (jj == 0) ? e0 : (jj == 1) ? e1 : (jj == 2) ? e2 : eb;
            if (jj < 4) E[rl][h * 4 + jj] = coef * rd;
        }
        __syncthreads();

        const int j0 = t * 2;
        const float* WTb = WT + (size_t)b * 512 * 32;
        float w0[32], w1[32];
#pragma unroll
        for (int s = 0; s < 32; ++s) {
            w0[s] = WTb[(size_t)j0 * 32 + s];
            w1[s] = WTb[(size_t)(j0 + 1) * 32 + s];
        }
        const float b0 = bo[j0], b1 = bo[j0 + 1];
#pragma unroll
        for (int rl = 0; rl < 16; ++rl) {
            float a0 = b0, a1 = b1;
#pragma unroll
            for (int s = 0; s < 32; ++s) {
                const float e = E[rl][s];
                a0 = fmaf(e, w0[s], a0);
                a1 = fmaf(e, w1[s], a1);
            }
            *(float2*)(out + (size_t)(r0 + rl) * EMBED + j0) = make_float2(a0, a1);
        }
    }
}

// ===========================================================================
// Fallback path: the verified R0 4-kernel pipeline (byte-exact).
// ===========================================================================
__global__ __launch_bounds__(256) void prep_kernel(
    const float* __restrict__ x,
    const float* __restrict__ Wq, const float* __restrict__ Wk,
    const float* __restrict__ Wv,
    u16* __restrict__ xb, u16* __restrict__ Wcat)
{
    const long long e0 = (long long)(blockIdx.x * 256 + threadIdx.x) * 8;
    const float* src;
    u16* dst;
    if (e0 < XELEMS) {
        src = x + e0; dst = xb + e0;
    } else {
        const long long j = e0 - XELEMS;
        const int row = (int)(j >> 9);
        const int col = (int)(j & 511);
        const int sel = row >> 9;
        const int r   = row & 511;
        const float* W = (sel == 0) ? Wq : (sel == 1) ? Wk : Wv;
        src = W + (size_t)r * EMBED + col; dst = Wcat + j;
    }
    float4 a = *(const float4*)(src);
    float4 b = *(const float4*)(src + 4);
    union { u16 u[8]; uint4 v; } p;
    p.u[0] = f2bf(a.x); p.u[1] = f2bf(a.y); p.u[2] = f2bf(a.z); p.u[3] = f2bf(a.w);
    p.u[4] = f2bf(b.x); p.u[5] = f2bf(b.y); p.u[6] = f2bf(b.z); p.u[7] = f2bf(b.w);
    *(uint4*)(dst) = p.v;
}

__global__ __launch_bounds__(256) void gemm_qkv_mfma(
    const u16* __restrict__ A, const u16* __restrict__ W,
    const float* __restrict__ bq, const float* __restrict__ bk,
    const float* __restrict__ bvv,
    u16* __restrict__ QKb, float* __restrict__ Vhead,
    float* __restrict__ vpart)
{
    __shared__ __align__(16) u16 As[128 * 64];
    __shared__ __align__(16) u16 Bs[64 * 64];

    const int m0 = (blockIdx.x & 31) * 128;
    const int n0 = (blockIdx.x >> 5) * 64;
    const int sel = n0 >> 9;
    const float* bias = ((sel == 0) ? bq : (sel == 1) ? bk : bvv) + (n0 & 511);

    const int t    = threadIdx.x;
    const int wave = t >> 6, lane = t & 63;
    const int wm   = wave >> 1, wn = wave & 1;
    const int qd   = lane >> 4, lr = lane & 15;

    const int sr8 = lane >> 3;
    const int sg  = (lane & 7) ^ sr8;
    const int soff = sg * 8;

    f32x4 acc[4][2] = {};

    const u16* Ag = A + (size_t)m0 * EMBED;
    const u16* Wg = W + (size_t)n0 * EMBED;

    u16* Adst = As + (size_t)(wave * 8) * 64;
    u16* Bdst = Bs + (size_t)(wave * 8) * 64;
    const u16* Asrc = Ag + (size_t)(wave * 8 + sr8) * EMBED + soff;
    const u16* Bsrc = Wg + (size_t)(wave * 8 + sr8) * EMBED + soff;

    for (int kc = 0; kc < EMBED; kc += 64) {
#pragma unroll
        for (int j = 0; j < 4; ++j)
            __builtin_amdgcn_global_load_lds(
                (const __attribute__((address_space(1))) void*)(Asrc + kc + (size_t)j * 32 * EMBED),
                (__attribute__((address_space(3))) void*)(Adst + j * 32 * 64), 16, 0, 0);
#pragma unroll
        for (int j = 0; j < 2; ++j)
            __builtin_amdgcn_global_load_lds(
                (const __attribute__((address_space(1))) void*)(Bsrc + kc + (size_t)j * 32 * EMBED),
                (__attribute__((address_space(3))) void*)(Bdst + j * 32 * 64), 16, 0, 0);
        __syncthreads();

#pragma unroll
        for (int kk = 0; kk < 2; ++kk) {
            const int gr = ((kk * 4 + qd) ^ (lr & 7)) * 8;
            bf16x8 af[4], bfr[2];
#pragma unroll
            for (int i = 0; i < 4; ++i)
                af[i]  = *(const bf16x8*)&As[(wm * 64 + i * 16 + lr) * 64 + gr];
#pragma unroll
            for (int i = 0; i < 2; ++i)
                bfr[i] = *(const bf16x8*)&Bs[(wn * 32 + i * 16 + lr) * 64 + gr];
#pragma unroll
            for (int mi = 0; mi < 4; ++mi)
#pragma unroll
                for (int ni = 0; ni < 2; ++ni)
                    acc[mi][ni] = __builtin_amdgcn_mfma_f32_16x16x32_bf16(
                        af[mi], bfr[ni], acc[mi][ni], 0, 0, 0);
        }
        __syncthreads();
    }

    if (sel < 2) {
#pragma unroll
        for (int ni = 0; ni < 2; ++ni) {
            const int cl = wn * 32 + ni * 16 + lr;
            const float bb = bias[cl];
#pragma unroll
            for (int mi = 0; mi < 4; ++mi)
#pragma unroll
                for (int e = 0; e < 4; ++e) {
                    const int row = m0 + wm * 64 + mi * 16 + qd * 4 + e;
                    QKb[(size_t)row * 1024 + n0 + cl] = f2bf(acc[mi][ni][e] + bb);
                }
        }
    } else {
        const int batch = m0 >> 11;
        const int mtb   = (m0 >> 7) & 15;
#pragma unroll
        for (int ni = 0; ni < 2; ++ni) {
            const int cl  = wn * 32 + ni * 16 + lr;
            const int col = (n0 - 1024) + cl;
            const float bb = bias[cl];
            float s = 0.f;
#pragma unroll
            for (int mi = 0; mi < 4; ++mi)
#pragma unroll
                for (int e = 0; e < 4; ++e) {
                    const int row = m0 + wm * 64 + mi * 16 + qd * 4 + e;
                    s += acc[mi][ni][e];
                    if ((row & (NSEQ - 1)) < 3)
                        Vhead[(size_t)batch * 1536 + (row & (NSEQ - 1)) * 512 + col]
                            = acc[mi][ni][e] + bb;
                }
            s += __shfl_xor(s, 16);
            s += __shfl_xor(s, 32);
            if (qd == 0)
                vpart[((size_t)batch * 512 + col) * 32 + mtb * 2 + wm] = s;
        }
    }
}

__global__ __launch_bounds__(256) void wsmall_kernel(
    const float* __restrict__ Vhead, const float* __restrict__ vpart,
    const float* __restrict__ bv,
    const float* __restrict__ Wo, float* __restrict__ WT)
{
    __shared__ float Vsm[4][512];
    const int b  = blockIdx.x >> 6;
    const int jb = blockIdx.x & 63;
    const int t  = threadIdx.x;

    for (int idx = t; idx < 512; idx += 256) {
        const float v0 = Vhead[(size_t)b * 1536 + idx];
        const float v1 = Vhead[(size_t)b * 1536 + 512 + idx];
        const float v2 = Vhead[(size_t)b * 1536 + 1024 + idx];
        float sum = 0.f;
        const float* vp = vpart + ((size_t)b * 512 + idx) * 32;
#pragma unroll
        for (int s = 0; s < 32; ++s) sum += vp[s];
        Vsm[0][idx] = v0; Vsm[1][idx] = v1; Vsm[2][idx] = v2;
        Vsm[3][idx] = sum + (float)NSEQ * bv[idx] - (v0 + v1 + v2);
    }
    __syncthreads();

    const int j  = jb * 8 + (t >> 5);
    const int s  = t & 31;
    const int h  = s >> 2, tt = s & 3;
    const float* Wor = Wo + (size_t)j * EMBED + h * 64;
    const float* vr  = &Vsm[tt][h * 64];
    float acc = 0.f;
#pragma unroll
    for (int c = 0; c < 64; ++c) {
        const int cc = (c + 2 * s) & 63;
        acc = fmaf(vr[cc], Wor[cc], acc);
    }
    WT[((size_t)b * 512 + j) * 32 + s] = acc;
}

__global__ __launch_bounds__(256) void attn_out_kernel(
    const u16* __restrict__ QKb, const float* __restrict__ WT,
    const float* __restrict__ bo, float* __restrict__ out)
{
    __shared__ float E[16][32];
    const int r0   = blockIdx.x * 16;
    const int b    = r0 >> 11;
    const int wave = threadIdx.x >> 6, lane = threadIdx.x & 63;
    const int d0   = lane * 8;

#pragma unroll
    for (int i = 0; i < 4; ++i) {
        const int rl = wave * 4 + i;
        const int r  = r0 + rl;
        const int sr = r & (NSEQ - 1);
        const u16* Qr = QKb + (size_t)r * 1024 + d0;
        const u16* Kr = QKb + (size_t)r * 1024 + 512 + d0;

        ushort8 qv = *(const ushort8*)Qr;
        ushort8 kv = *(const ushort8*)Kr;
        float q[8], k[8];
#pragma unroll
        for (int z = 0; z < 8; ++z) { q[z] = bf2f(qv[z]); k[z] = bf2f(kv[z]); }

        float s1 = 0.f;
#pragma unroll
        for (int z = 0; z < 8; ++z) s1 = fmaf(q[z], k[z], s1);

        float s0 = 0.f, s2 = 0.f;
        if (sr > 0) {
            ushort8 pv = *(const ushort8*)(Kr - 1024);
#pragma unroll
            for (int z = 0; z < 8; ++z) s0 = fmaf(q[z], bf2f(pv[z]), s0);
        }
        if (sr < NSEQ - 1) {
            ushort8 nv = *(const ushort8*)(Kr + 1024);
#pragma unroll
            for (int z = 0; z < 8; ++z) s2 = fmaf(q[z], bf2f(nv[z]), s2);
        }
#pragma unroll
        for (int off = 1; off <= 4; off <<= 1) {
            s0 += __shfl_xor(s0, off);
            s1 += __shfl_xor(s1, off);
            s2 += __shfl_xor(s2, off);
        }
        const float m  = fmaxf(fmaxf(s0, s1), fmaxf(s2, 0.f));
        const float e0 = __expf(s0 - m);
        const float e1 = __expf(s1 - m);
        const float e2 = __expf(s2 - m);
        const float eb = __expf(-m);
        const float rd = 1.f / (e0 + e1 + e2 + (float)(NSEQ - 3) * eb);
        const int h = lane >> 3, jj = lane & 7;
        const float coef = (jj == 0) ? e0 : (jj == 1) ? e1 : (jj == 2) ? e2 : eb;
        if (jj < 4) E[rl][h * 4 + jj] = coef * rd;
    }
    __syncthreads();

    const int j0 = threadIdx.x * 2;
    const float* WTb = WT + (size_t)b * 512 * 32;
    float w0[32], w1[32];
#pragma unroll
    for (int s = 0; s < 32; ++s) {
        w0[s] = WTb[(size_t)j0 * 32 + s];
        w1[s] = WTb[(size_t)(j0 + 1) * 32 + s];
    }
    const float b0 = bo[j0], b1 = bo[j0 + 1];
#pragma unroll
    for (int rl = 0; rl < 16; ++rl) {
        float a0 = b0, a1 = b1;
#pragma unroll
        for (int s = 0; s < 32; ++s) {
            const float e = E[rl][s];
            a0 = fmaf(e, w0[s], a0);
            a1 = fmaf(e, w1[s], a1);
        }
        float2 o = make_float2(a0, a1);
        *(float2*)(out + (size_t)(r0 + rl) * EMBED + j0) = o;
    }
}

extern "C" void kernel_launch(void* const* d_in, const int* in_sizes, int n_in,
                              void* d_out, int out_size, void* d_ws, size_t ws_size,
                              hipStream_t stream)
{
    const float* x  = (const float*)d_in[0];
    const float* Wq = (const float*)d_in[1];
    const float* bq = (const float*)d_in[2];
    const float* Wk = (const float*)d_in[3];
    const float* bk = (const float*)d_in[4];
    const float* Wv = (const float*)d_in[5];
    const float* bv = (const float*)d_in[6];
    const float* Wo = (const float*)d_in[7];
    const float* bo = (const float*)d_in[8];
    float* out = (float*)d_out;

    u16*   QKb   = (u16*)d_ws;                     // 4096*1024 u16 (Q|K bf16)
    u16*   xb    = QKb + (size_t)NROWS * 1024;     // 2097152 bf16
    u16*   Wcat  = xb + XELEMS;                    // 786432 bf16
    float* Vhead = (float*)(Wcat + WCATELEMS);     // 2*3*512 f32
    float* vpart = Vhead + 2 * 3 * 512;            // 2*512*32 f32 (write-once)
    float* WT    = vpart + 2 * 512 * 32;           // 2*512*32 f32

    // Decide once (host-side queries only; capture-safe).
    static int use_coop = -1;
    if (use_coop < 0) {
        int dev = 0;
        (void)hipGetDevice(&dev);
        int sup = 0;
        (void)hipDeviceGetAttribute(&sup, hipDeviceAttributeCooperativeLaunch, dev);
        int maxb = 0;
        (void)hipOccupancyMaxActiveBlocksPerMultiprocessor(&maxb, fused_all, 256, 0);
        use_coop = (sup && maxb >= 3) ? 1 : 0;
    }

    if (use_coop) {
        void* args[] = { (void*)&x, (void*)&Wq, (void*)&Wk, (void*)&Wv,
                         (void*)&bq, (void*)&bk, (void*)&bv, (void*)&Wo,
                         (void*)&bo, (void*)&xb, (void*)&Wcat, (void*)&QKb,
                         (void*)&Vhead, (void*)&vpart, (void*)&WT, (void*)&out };
        (void)hipLaunchCooperativeKernel((void*)fused_all, dim3(768), dim3(256),
                                         args, 0, stream);
    } else {
        prep_kernel<<<NCONVB, 256, 0, stream>>>(x, Wq, Wk, Wv, xb, Wcat);
        gemm_qkv_mfma<<<768, 256, 0, stream>>>(xb, Wcat, bq, bk, bv, QKb, Vhead, vpart);
        wsmall_kernel<<<128, 256, 0, stream>>>(Vhead, vpart, bv, Wo, WT);
        attn_out_kernel<<<256, 256, 0, stream>>>(QKb, WT, bo, out);
    }
}